// Round 11
// baseline (1718.085 us; speedup 1.0000x reference)
//
#include <hip/hip_runtime.h>

#define NN 4096
#define NPOINTS 1024
#define NSAMP 32
#define MROWS (16*NPOINTS*NSAMP)      // 524288
#define NPAIRS (MROWS/32)             // 16384
#define OUT2_OFF (16*NPOINTS*3)       // 49152
#define EPSF 1e-5f
#define RPB 128                       // rows per stats block (legacy k_stage)
#define NBLK 4096                     // legacy stats blocks

typedef unsigned long long ull;
using f32x4  = __attribute__((ext_vector_type(4))) float;
using bf16x8 = __attribute__((ext_vector_type(8))) short;

// ---------- bf16 helpers ----------
__device__ __forceinline__ float bflo(unsigned int u){ union{unsigned int i; float f;} v; v.i = u << 16; return v.f; }
__device__ __forceinline__ float bfhi(unsigned int u){ union{unsigned int i; float f;} v; v.i = u & 0xffff0000u; return v.f; }
__device__ __forceinline__ unsigned short f2bf(float f){
  union{float f; unsigned int i;} v; v.f = f;
  unsigned int r = v.i + 0x7fffu + ((v.i >> 16) & 1u);
  return (unsigned short)(r >> 16);
}

__device__ __forceinline__ unsigned short packhl(float v, int isLo){
  unsigned short h = f2bf(v);
  if (isLo){ float r = __fsub_rn(v, bflo((unsigned)h)); h = f2bf(r); }
  return h;
}

// ---------- FPS: r3/r9 version, measured 665 us (parked at structural floor;
// r4 256thr, r7 2-batch, r10 packed variants all measured slower) ----------
__global__ __launch_bounds__(512) void k_fps(const float* __restrict__ xyz,
    float* __restrict__ nxyz, float* __restrict__ out){
  __shared__ float xs[NN], ys[NN], zs[NN];
  __shared__ ull wbest[2][8];
  const int b = blockIdx.x, t = threadIdx.x;
  const float* xb = xyz + (size_t)b*NN*3;
  for (int j = t; j < NN; j += 512){
    xs[j] = xb[j*3+0]; ys[j] = xb[j*3+1]; zs[j] = xb[j*3+2];
  }
  __syncthreads();
  float px[8], py[8], pz[8], pd[8];
  #pragma unroll
  for (int j=0;j<8;j++){ int i=j*512+t; px[j]=xs[i]; py[j]=ys[i]; pz[j]=zs[i]; pd[j]=1e10f; }
  int cur = 0;
  const int lane = t & 63, wv = t >> 6;
  for (int it=0; it<NPOINTS; ++it){
    float lx = xs[cur], ly = ys[cur], lz = zs[cur];
    if (t == 0){
      int o = (b*NPOINTS + it)*3;
      nxyz[o]=lx; nxyz[o+1]=ly; nxyz[o+2]=lz;
      out[o]=lx;  out[o+1]=ly;  out[o+2]=lz;
    }
    float bv = -1.0f; int bi = 0;
    #pragma unroll
    for (int j=0;j<8;j++){
      float dx = __fsub_rn(px[j], lx);
      float dy = __fsub_rn(py[j], ly);
      float dz = __fsub_rn(pz[j], lz);
      float d  = __fadd_rn(__fadd_rn(__fmul_rn(dx,dx), __fmul_rn(dy,dy)), __fmul_rn(dz,dz));
      float nd = fminf(pd[j], d);
      pd[j] = nd;
      if (nd > bv){ bv = nd; bi = j*512 + t; }
    }
    ull key = ((ull)__float_as_uint(bv) << 32) | (ull)(0xFFFFFFFFu - (unsigned)bi);
    #define DPPSTEP(ctrl, rmask) { \
      unsigned int tlo = __builtin_amdgcn_update_dpp(0, (int)(unsigned int)(key & 0xFFFFFFFFull), ctrl, rmask, 0xf, false); \
      unsigned int thi = __builtin_amdgcn_update_dpp(0, (int)(unsigned int)(key >> 32), ctrl, rmask, 0xf, false); \
      ull tk = ((ull)thi << 32) | (ull)tlo; \
      if (tk > key) key = tk; }
    DPPSTEP(0x111, 0xf)
    DPPSTEP(0x112, 0xf)
    DPPSTEP(0x114, 0xf)
    DPPSTEP(0x118, 0xf)
    DPPSTEP(0x142, 0xa)
    DPPSTEP(0x143, 0xc)
    #undef DPPSTEP
    if (lane == 63) wbest[it & 1][wv] = key;
    __syncthreads();
    ull best = wbest[it & 1][0];
    #pragma unroll
    for (int w=1; w<8; w++){
      ull ok = wbest[it & 1][w];
      if (ok > best) best = ok;
    }
    cur = (int)(0xFFFFFFFFu - (unsigned)(best & 0xFFFFFFFFull));
  }
}

// ---------- fused post-FPS pre-pass: featT (blocks 0..1023) + weight packs
// (1024..1055) + ball query (1056..5151). All throughput-bound, 256 thr;
// co-residency harmless (unlike fusing with issue-bound FPS, r10 lesson).
__global__ __launch_bounds__(256) void k_pb(
    const float* __restrict__ xyz, const float* __restrict__ nxyz, int* __restrict__ ball_idx,
    const float* __restrict__ feat, unsigned short* __restrict__ featT,
    const float* __restrict__ W1, const float* __restrict__ W2, const float* __restrict__ W3,
    float* __restrict__ W1T, float* __restrict__ W2T, float* __restrict__ W3T,
    unsigned short* __restrict__ w1p, unsigned short* __restrict__ w2p, unsigned short* __restrict__ w3p)
{
  __shared__ float tile[64*65];
  const int bid = blockIdx.x;
  const int t = threadIdx.x;
  if (bid < 1024){
    // ---- featT: (B,64,N) fp32 -> (B,N,64) bf16 (exact k_ft) ----
    const int b = bid >> 6, n0 = (bid & 63) << 6;
    const int nl = t & 63, cb = t >> 6;
    #pragma unroll
    for (int k=0;k<16;k++){
      int c = cb + (k<<2);
      tile[c*65 + nl] = feat[((size_t)(b*64 + c))*NN + n0 + nl];
    }
    __syncthreads();
    #pragma unroll
    for (int k=0;k<16;k++){
      int nl2 = cb + (k<<2);
      featT[((size_t)(b*NN) + n0 + nl2)*64 + nl] = f2bf(tile[nl*65 + nl2]);
    }
  } else if (bid < 1056){
    // ---- weight transposes + MFMA B-fragment packs (exact k_wt) ----
    int g = (bid - 1024)*256 + t;            // 0..8191
    if (g < 67*64){ int c = g >> 6, o = g & 63;  W1T[g] = W1[o*67 + c]; }
    if (g < 64*64){ int c = g >> 6, o = g & 63;  W2T[g] = W2[o*64 + c]; }
    if (g < 64*128){ int c = g >> 7, o = g & 127; W3T[g] = W3[o*64 + c]; }
    if (g < 1024){   // W1 feat part (cols 3..66): NTG=4 -> 16 frags
      int f=g>>6, l=g&63, isLo=f>>3, f0=f&7, kf=f0>>2, ntg=f0&3;
      const float* src = W1 + (ntg*16+(l&15))*67 + 3 + kf*32 + ((l>>4)*8);
      unsigned short* dst = w1p + ((size_t)f*64 + l)*8;
      #pragma unroll
      for (int j=0;j<8;j++) dst[j] = packhl(src[j], isLo);
    }
    if (g < 1024){   // W2
      int f=g>>6, l=g&63, isLo=f>>3, f0=f&7, kf=f0>>2, ntg=f0&3;
      const float* src = W2 + (ntg*16+(l&15))*64 + kf*32 + ((l>>4)*8);
      unsigned short* dst = w2p + ((size_t)f*64 + l)*8;
      #pragma unroll
      for (int j=0;j<8;j++) dst[j] = packhl(src[j], isLo);
    }
    if (g < 2048){   // W3
      int f=g>>6, l=g&63, isLo=f>>4, f0=f&15, kf=f0>>3, ntg=f0&7;
      const float* src = W3 + (ntg*16+(l&15))*64 + kf*32 + ((l>>4)*8);
      unsigned short* dst = w3p + ((size_t)f*64 + l)*8;
      #pragma unroll
      for (int j=0;j<8;j++) dst[j] = packhl(src[j], isLo);
    }
  } else {
    // ---- ball query: wave-per-query, ballot/prefix first-32 (exact r9 k_ball) ----
    const int lane = t & 63;
    const int q = (bid - 1056)*4 + (t >> 6);  // 16384 queries
    const int b = q >> 10;
    const float* xb = xyz + (size_t)b*NN*3;
    const int co = q*3;
    const float cx = nxyz[co], cy = nxyz[co+1], cz = nxyz[co+2];
    const int base = q*NSAMP;
    const float R2 = 0.04f;
    int cnt = 0, first = 0;
    for (int i0 = 0; i0 < NN; i0 += 64){
      const int i = i0 + lane;
      float lx = xb[i*3+0], ly = xb[i*3+1], lz = xb[i*3+2];
      float dx = __fsub_rn(cx, lx);
      float dy = __fsub_rn(cy, ly);
      float dz = __fsub_rn(cz, lz);
      float d2 = __fadd_rn(__fadd_rn(__fmul_rn(dx,dx), __fmul_rn(dy,dy)), __fmul_rn(dz,dz));
      const bool in = (d2 < R2);
      ull mask = __ballot(in);
      if (mask){
        if (cnt == 0) first = i0 + (int)__ffsll((long long)mask) - 1;
        int slot = cnt + (int)__popcll(mask & ((1ull << lane) - 1ull));
        if (in && slot < NSAMP) ball_idx[base + slot] = i;
        cnt += (int)__popcll(mask);
        if (cnt >= NSAMP) break;
      }
    }
    if (lane >= cnt && lane < NSAMP) ball_idx[base + lane] = first;
  }
}

// ---------- last-block BN finalize helper ----------
template<int C>
__device__ __forceinline__ void fin_lastblock(float* __restrict__ sums,
    unsigned int* __restrict__ cnt, const float* __restrict__ g,
    const float* __restrict__ bvec, float* __restrict__ scale,
    float* __restrict__ shift, int t, int nblocks)
{
  __shared__ int isLast;
  __threadfence();
  __syncthreads();
  if (t == 0) isLast = (atomicAdd(cnt, 1u) == (unsigned)(nblocks - 1));
  __syncthreads();
  if (isLast && t < C){
    float s  = atomicAdd(&sums[t], 0.f);          // atomic read: device-coherent
    float qq = atomicAdd(&sums[C + t], 0.f);
    float m  = s  * (1.f/(float)MROWS);
    float vv = qq * (1.f/(float)MROWS) - m*m;
    float sc = g[t] / sqrtf(vv + EPSF);
    scale[t] = sc;
    shift[t] = bvec[t] - m*sc;
  }
}

// ---------- row producers (legacy fallback path) ----------
__device__ __forceinline__ void gather_y1(int r,
    const float* __restrict__ xyz, const unsigned short* __restrict__ featT,
    const float* __restrict__ nxyz, const int* __restrict__ ball_idx,
    const float* __restrict__ W1T, float* __restrict__ y)
{
  const int b = r >> 15;
  const int p = (r >> 5) & (NPOINTS-1);
  const int i = ball_idx[r];
  const int co = (b*NPOINTS + p)*3;
  const float* xp = xyz + ((size_t)(b*NN + i))*3;
  const float h0 = __fsub_rn(xp[0], nxyz[co]);
  const float h1 = __fsub_rn(xp[1], nxyz[co+1]);
  const float h2 = __fsub_rn(xp[2], nxyz[co+2]);
  #pragma unroll
  for (int o=0;o<64;o++) y[o] = h0 * W1T[o];
  #pragma unroll
  for (int o=0;o<64;o++) y[o] = fmaf(h1, W1T[64+o], y[o]);
  #pragma unroll
  for (int o=0;o<64;o++) y[o] = fmaf(h2, W1T[128+o], y[o]);
  const uint4* fp = (const uint4*)(featT + ((size_t)(b*NN + i))*64);
  #pragma unroll
  for (int c8=0;c8<8;c8++){
    const uint4 u = fp[c8];
    float fv[8];
    fv[0]=bflo(u.x); fv[1]=bfhi(u.x); fv[2]=bflo(u.y); fv[3]=bfhi(u.y);
    fv[4]=bflo(u.z); fv[5]=bfhi(u.z); fv[6]=bflo(u.w); fv[7]=bfhi(u.w);
    const float* wb = W1T + (3 + c8*8)*64;
    #pragma unroll
    for (int k=0;k<8;k++){
      #pragma unroll
      for (int o=0;o<64;o++) y[o] = fmaf(fv[k], wb[k*64+o], y[o]);
    }
  }
}

__device__ __forceinline__ void load_act(const unsigned short* __restrict__ act, int r, float* __restrict__ y){
  const uint4* p = (const uint4*)(act + (size_t)r*64);
  #pragma unroll
  for (int j=0;j<8;j++){
    uint4 u = p[j];
    y[j*8+0]=bflo(u.x); y[j*8+1]=bfhi(u.x); y[j*8+2]=bflo(u.y); y[j*8+3]=bfhi(u.y);
    y[j*8+4]=bflo(u.z); y[j*8+5]=bfhi(u.z); y[j*8+6]=bflo(u.w); y[j*8+7]=bfhi(u.w);
  }
}

__device__ __forceinline__ void store_bf16x64(unsigned short* __restrict__ dst, const float* __restrict__ y){
  uint4* row = (uint4*)dst;
  #pragma unroll
  for (int j=0;j<8;j++){
    union { uint4 u; unsigned short h[8]; } pk;
    #pragma unroll
    for (int k=0;k<8;k++) pk.h[k] = f2bf(y[j*8+k]);
    row[j] = pk.u;
  }
}

__device__ __forceinline__ void bnrelu64(float* __restrict__ y,
    const float* __restrict__ sc, const float* __restrict__ sh){
  #pragma unroll
  for (int o=0;o<64;o++) y[o] = fmaxf(0.f, fmaf(y[o], sc[o], sh[o]));
}

template<int LDW>
__device__ __forceinline__ void gemm64(const float* __restrict__ a, const float* __restrict__ WT,
                                       float* __restrict__ out){
  #pragma unroll
  for (int o=0;o<64;o++) out[o] = 0.f;
  #pragma unroll 4
  for (int c=0;c<64;c++){
    const float av = a[c];
    const float* wb = WT + c*LDW;
    #pragma unroll
    for (int o=0;o<64;o++) out[o] = fmaf(av, wb[o], out[o]);
  }
}

__device__ __forceinline__ void stats_tile(float* tile, int t, const float* __restrict__ y,
                                           float& s, float& q){
  #pragma unroll
  for (int j=0;j<64;j++) tile[t*65 + j] = y[j];
  __syncthreads();
  #pragma unroll 8
  for (int r=0;r<64;r++){
    float v = tile[r*65 + t];
    s += v; q = fmaf(v, v, q);
  }
  __syncthreads();
}

// ---------- legacy fused stage kernels (tier<2 fallback) ----------
template<int STAGE, int SRC, bool STORE>
__global__ __launch_bounds__(64) void k_stage(
    const float* __restrict__ xyz, const unsigned short* __restrict__ featT,
    const float* __restrict__ nxyz, const int* __restrict__ ball_idx,
    const unsigned short* __restrict__ actin, unsigned short* __restrict__ actout,
    const float* __restrict__ W1T, const float* __restrict__ W2T, const float* __restrict__ W3T,
    const float* __restrict__ sc1, const float* __restrict__ sh1,
    const float* __restrict__ sc2, const float* __restrict__ sh2,
    float* __restrict__ sums)
{
  __shared__ float tile[64*65];
  const int t = threadIdx.x;
  float s0=0.f, q0=0.f, s1=0.f, q1=0.f;
  for (int it=0; it<RPB/64; ++it){
    const int r = blockIdx.x*RPB + it*64 + t;
    float y[64];
    if constexpr (SRC == 0) gather_y1(r, xyz, featT, nxyz, ball_idx, W1T, y);
    else                    load_act(actin, r, y);
    if constexpr (STAGE == 1){
      if constexpr (STORE) store_bf16x64(actout + (size_t)r*64, y);
      stats_tile(tile, t, y, s0, q0);
    } else if constexpr (STAGE == 2){
      bnrelu64(y, sc1, sh1);
      float y2[64];
      gemm64<64>(y, W2T, y2);
      if constexpr (STORE) store_bf16x64(actout + (size_t)r*64, y2);
      stats_tile(tile, t, y2, s0, q0);
    } else {
      float a2[64];
      if constexpr (SRC != 2){
        bnrelu64(y, sc1, sh1);
        gemm64<64>(y, W2T, a2);
      } else {
        #pragma unroll
        for (int o=0;o<64;o++) a2[o] = y[o];
      }
      bnrelu64(a2, sc2, sh2);
      float y3[64];
      gemm64<128>(a2, W3T, y3);
      if constexpr (STORE) store_bf16x64(actout + (size_t)r*128, y3);
      stats_tile(tile, t, y3, s0, q0);
      gemm64<128>(a2, W3T + 64, y3);
      if constexpr (STORE) store_bf16x64(actout + (size_t)r*128 + 64, y3);
      stats_tile(tile, t, y3, s1, q1);
    }
  }
  if constexpr (STAGE < 3){
    atomicAdd(&sums[t], s0);
    atomicAdd(&sums[64 + t], q0);
  } else {
    atomicAdd(&sums[t], s0);
    atomicAdd(&sums[64 + t], s1);
    atomicAdd(&sums[128 + t], q0);
    atomicAdd(&sums[192 + t], q1);
  }
}

// ---------- standalone BN finalize (fallback path) ----------
template<int C>
__global__ void k_fin(const float* __restrict__ sums,
    const float* __restrict__ g, const float* __restrict__ bv,
    float* __restrict__ scale, float* __restrict__ shift)
{
  const int c = threadIdx.x;
  float m  = sums[c]   * (1.f/(float)MROWS);
  float vv = sums[C+c] * (1.f/(float)MROWS) - m*m;
  float sc = g[c] / sqrtf(vv + EPSF);
  scale[c] = sc;
  shift[c] = bv[c] - m*sc;
}

// ---------- MFMA stage1: y1 = [h|feat] @ W1^T, store act1, stats1, fin1 fused ----------
__global__ __launch_bounds__(256) void k_mg1(
    const float* __restrict__ xyz, const unsigned short* __restrict__ featT,
    const float* __restrict__ nxyz, const int* __restrict__ ball_idx,
    const unsigned short* __restrict__ w1p, const float* __restrict__ W1T,
    unsigned short* __restrict__ act1, float* __restrict__ sums,
    unsigned int* __restrict__ cnt, const float* __restrict__ g1,
    const float* __restrict__ b1, float* __restrict__ sc1, float* __restrict__ sh1)
{
  __shared__ float hxs[256], hys[256], hzs[256];
  __shared__ float w1s[192];
  __shared__ float lsum[128];
  const int t = threadIdx.x, lane = t & 63, wv = t >> 6;
  const int blkrow = blockIdx.x*256;
  {  // phase A: one row per thread -> h into LDS
    int r = blkrow + t;
    int b = r >> 15, p = (r >> 5) & (NPOINTS-1), i = ball_idx[r];
    const float* xp = xyz + ((size_t)(b*NN + i))*3;
    int co = (b*NPOINTS + p)*3;
    hxs[t] = __fsub_rn(xp[0], nxyz[co]);
    hys[t] = __fsub_rn(xp[1], nxyz[co+1]);
    hzs[t] = __fsub_rn(xp[2], nxyz[co+2]);
  }
  if (t < 192) w1s[t] = W1T[t];
  if (t < 128) lsum[t] = 0.f;
  __syncthreads();
  const int rowbase = blkrow + wv*64;
  const int kc0 = (lane>>4)*8;
  bf16x8 A[4][2];
  #pragma unroll
  for (int mt=0;mt<4;mt++){
    int r = rowbase + mt*16 + (lane&15);
    int b = r >> 15, i = ball_idx[r];
    const unsigned short* fp = featT + ((size_t)(b*NN + i))*64 + kc0;
    A[mt][0] = *(const bf16x8*)(fp);
    A[mt][1] = *(const bf16x8*)(fp + 32);
  }
  bf16x8 Bh[2][4], Bl[2][4];
  #pragma unroll
  for (int kf=0;kf<2;kf++)
    #pragma unroll
    for (int nt=0;nt<4;nt++){
      Bh[kf][nt] = *(const bf16x8*)(w1p + ((size_t)(kf*4+nt)*64 + lane)*8);
      Bl[kf][nt] = *(const bf16x8*)(w1p + ((size_t)(8 + kf*4+nt)*64 + lane)*8);
    }
  f32x4 c[4][4];
  const int lr0 = wv*64 + (lane>>4)*4;
  #pragma unroll
  for (int nt=0;nt<4;nt++){
    int col = nt*16 + (lane&15);
    float w0 = w1s[col], w1 = w1s[64+col], w2 = w1s[128+col];
    #pragma unroll
    for (int mt=0;mt<4;mt++)
      #pragma unroll
      for (int rr=0;rr<4;rr++){
        int lr = lr0 + mt*16 + rr;
        c[mt][nt][rr] = fmaf(hzs[lr], w2, fmaf(hys[lr], w1, hxs[lr]*w0));
      }
  }
  #pragma unroll
  for (int mt=0;mt<4;mt++)
    #pragma unroll
    for (int nt=0;nt<4;nt++){
      f32x4 acc = c[mt][nt];
      acc = __builtin_amdgcn_mfma_f32_16x16x32_bf16(A[mt][0], Bh[0][nt], acc, 0,0,0);
      acc = __builtin_amdgcn_mfma_f32_16x16x32_bf16(A[mt][1], Bh[1][nt], acc, 0,0,0);
      acc = __builtin_amdgcn_mfma_f32_16x16x32_bf16(A[mt][0], Bl[0][nt], acc, 0,0,0);
      acc = __builtin_amdgcn_mfma_f32_16x16x32_bf16(A[mt][1], Bl[1][nt], acc, 0,0,0);
      c[mt][nt] = acc;
    }
  #pragma unroll
  for (int nt=0;nt<4;nt++){
    float s=0.f, q=0.f;
    #pragma unroll
    for (int mt=0;mt<4;mt++)
      #pragma unroll
      for (int rr=0;rr<4;rr++){ float v=c[mt][nt][rr]; s+=v; q=fmaf(v,v,q); }
    s += __shfl_xor(s,16,64); s += __shfl_xor(s,32,64);
    q += __shfl_xor(q,16,64); q += __shfl_xor(q,32,64);
    if (lane<16){
      atomicAdd(&lsum[nt*16+lane], s);
      atomicAdd(&lsum[64 + nt*16+lane], q);
    }
  }
  #pragma unroll
  for (int nt=0;nt<4;nt++)
    #pragma unroll
    for (int mt=0;mt<4;mt++)
      #pragma unroll
      for (int rr=0;rr<4;rr++){
        int row = rowbase + mt*16 + (lane>>4)*4 + rr;
        act1[(size_t)row*64 + nt*16 + (lane&15)] = f2bf(c[mt][nt][rr]);
      }
  __syncthreads();
  if (t < 128) atomicAdd(&sums[t], lsum[t]);
  fin_lastblock<64>(sums, cnt, g1, b1, sc1, sh1, t, gridDim.x);
}

// ---------- MFMA stage GEMM: y = bnrelu(actin) @ W^T, fin fused ----------
__device__ __forceinline__ bf16x8 ldA_bn(const unsigned short* __restrict__ p,
    const float* __restrict__ sc, const float* __restrict__ sh){
  uint4 u = *(const uint4*)p;
  unsigned w[4] = {u.x, u.y, u.z, u.w};
  union { bf16x8 v; unsigned short h[8]; } o;
  #pragma unroll
  for (int q=0;q<4;q++){
    float lo = fmaxf(0.f, fmaf(bflo(w[q]), sc[2*q],   sh[2*q]));
    float hi = fmaxf(0.f, fmaf(bfhi(w[q]), sc[2*q+1], sh[2*q+1]));
    o.h[2*q]   = f2bf(lo);
    o.h[2*q+1] = f2bf(hi);
  }
  return o.v;
}

template<int NOUT, bool MINMAX>
__global__ __launch_bounds__(256) void k_mgemm(
    const unsigned short* __restrict__ actin,
    unsigned short* __restrict__ actout,
    const unsigned short* __restrict__ wp,
    const float* __restrict__ scp, const float* __restrict__ shp,
    float* __restrict__ sums,
    float* __restrict__ ymax, float* __restrict__ ymin,
    unsigned int* __restrict__ cnt, const float* __restrict__ g,
    const float* __restrict__ bvec, float* __restrict__ scale, float* __restrict__ shift)
{
  constexpr int NTG = NOUT/16;
  __shared__ float lsum[2*NOUT];
  const int t = threadIdx.x, lane = t & 63, wv = t >> 6;
  for (int i=t;i<2*NOUT;i+=256) lsum[i]=0.f;
  __syncthreads();
  const int rowbase = blockIdx.x*256 + wv*64;
  const int kc0 = (lane>>4)*8;
  float scl[16], shl[16];
  #pragma unroll
  for (int kf=0;kf<2;kf++)
    #pragma unroll
    for (int j=0;j<8;j++){
      scl[kf*8+j] = scp[kf*32+kc0+j];
      shl[kf*8+j] = shp[kf*32+kc0+j];
    }
  bf16x8 A[4][2];
  #pragma unroll
  for (int mt=0;mt<4;mt++)
    #pragma unroll
    for (int kf=0;kf<2;kf++)
      A[mt][kf] = ldA_bn(actin + ((size_t)(rowbase + mt*16 + (lane&15)))*64 + kf*32 + kc0,
                         &scl[kf*8], &shl[kf*8]);
  #pragma unroll
  for (int h=0; h<NOUT/64; h++){
    bf16x8 Bh[2][4], Bl[2][4];
    #pragma unroll
    for (int kf=0;kf<2;kf++)
      #pragma unroll
      for (int nt=0;nt<4;nt++){
        int ntg = h*4+nt;
        Bh[kf][nt] = *(const bf16x8*)(wp + ((size_t)(kf*NTG+ntg)*64 + lane)*8);
        Bl[kf][nt] = *(const bf16x8*)(wp + ((size_t)(2*NTG + kf*NTG+ntg)*64 + lane)*8);
      }
    f32x4 c[4][4];
    #pragma unroll
    for (int mt=0;mt<4;mt++)
      #pragma unroll
      for (int nt=0;nt<4;nt++){
        f32x4 acc = {0.f,0.f,0.f,0.f};
        acc = __builtin_amdgcn_mfma_f32_16x16x32_bf16(A[mt][0], Bh[0][nt], acc, 0,0,0);
        acc = __builtin_amdgcn_mfma_f32_16x16x32_bf16(A[mt][1], Bh[1][nt], acc, 0,0,0);
        acc = __builtin_amdgcn_mfma_f32_16x16x32_bf16(A[mt][0], Bl[0][nt], acc, 0,0,0);
        acc = __builtin_amdgcn_mfma_f32_16x16x32_bf16(A[mt][1], Bl[1][nt], acc, 0,0,0);
        c[mt][nt] = acc;
      }
    #pragma unroll
    for (int nt=0;nt<4;nt++){
      float s=0.f, q=0.f;
      #pragma unroll
      for (int mt=0;mt<4;mt++)
        #pragma unroll
        for (int r=0;r<4;r++){ float v=c[mt][nt][r]; s+=v; q=fmaf(v,v,q); }
      s += __shfl_xor(s,16,64); s += __shfl_xor(s,32,64);
      q += __shfl_xor(q,16,64); q += __shfl_xor(q,32,64);
      if (lane<16){
        atomicAdd(&lsum[h*64+nt*16+lane], s);
        atomicAdd(&lsum[NOUT + h*64+nt*16+lane], q);
      }
    }
    if constexpr (!MINMAX){
      #pragma unroll
      for (int nt=0;nt<4;nt++)
        #pragma unroll
        for (int mt=0;mt<4;mt++)
          #pragma unroll
          for (int r=0;r<4;r++){
            int row = rowbase + mt*16 + (lane>>4)*4 + r;
            actout[(size_t)row*NOUT + h*64 + nt*16 + (lane&15)] = f2bf(c[mt][nt][r]);
          }
    } else {
      #pragma unroll
      for (int nt=0;nt<4;nt++){
        float mx0=-1e30f, mn0=1e30f, mx1=-1e30f, mn1=1e30f;
        #pragma unroll
        for (int mt=0;mt<2;mt++)
          #pragma unroll
          for (int r=0;r<4;r++){ float v=c[mt][nt][r]; mx0=fmaxf(mx0,v); mn0=fminf(mn0,v); }
        #pragma unroll
        for (int mt=2;mt<4;mt++)
          #pragma unroll
          for (int r=0;r<4;r++){ float v=c[mt][nt][r]; mx1=fmaxf(mx1,v); mn1=fminf(mn1,v); }
        mx0=fmaxf(mx0,__shfl_xor(mx0,16,64)); mx0=fmaxf(mx0,__shfl_xor(mx0,32,64));
        mn0=fminf(mn0,__shfl_xor(mn0,16,64)); mn0=fminf(mn0,__shfl_xor(mn0,32,64));
        mx1=fmaxf(mx1,__shfl_xor(mx1,16,64)); mx1=fmaxf(mx1,__shfl_xor(mx1,32,64));
        mn1=fminf(mn1,__shfl_xor(mn1,16,64)); mn1=fminf(mn1,__shfl_xor(mn1,32,64));
        if (lane<16){
          int ch = h*64+nt*16+lane;
          int pair0 = rowbase>>5;
          float2 vx = {mx0, mx1}, vn = {mn0, mn1};
          *(float2*)(ymax + (size_t)ch*NPAIRS + pair0) = vx;
          *(float2*)(ymin + (size_t)ch*NPAIRS + pair0) = vn;
        }
      }
    }
  }
  __syncthreads();
  for (int i=t;i<2*NOUT;i+=256) atomicAdd(&sums[i], lsum[i]);
  fin_lastblock<NOUT>(sums, cnt, g, bvec, scale, shift, t, gridDim.x);
}

// ---------- tier2 final: bn3+relu applied to per-(pair,ch) extremum ----------
__global__ __launch_bounds__(256) void k_mx(const float* __restrict__ ymax,
    const float* __restrict__ ymin, const float* __restrict__ sc3,
    const float* __restrict__ sh3, float* __restrict__ out){
  int idx = blockIdx.x*256 + threadIdx.x;     // 16*128*1024
  int p = idx & 1023;
  int o = (idx>>10) & 127;
  int b = idx>>17;
  float sc = sc3[o], sh = sh3[o];
  size_t src = (size_t)o*NPAIRS + b*1024 + p;
  float v = (sc >= 0.f) ? ymax[src] : ymin[src];
  out[OUT2_OFF + ((size_t)(b*128+o))*1024 + p] = fmaxf(0.f, fmaf(v, sc, sh));
}

// ---------- fallback final pass (tier<2) ----------
template<bool FROMACT>
__global__ __launch_bounds__(64) void k_pass2(
    const float* __restrict__ xyz, const unsigned short* __restrict__ featT,
    const float* __restrict__ nxyz, const int* __restrict__ ball_idx,
    const unsigned short* __restrict__ act1,
    const float* __restrict__ W1T, const float* __restrict__ W2T,
    const float* __restrict__ W3,
    const float* __restrict__ sc1, const float* __restrict__ sh1,
    const float* __restrict__ sc2, const float* __restrict__ sh2,
    const float* __restrict__ sc3, const float* __restrict__ sh3,
    float* __restrict__ out)
{
  const int t = threadIdx.x;
  const int s = t & 31;
  const int pair = blockIdx.x*2 + (t >> 5);
  const int r = pair*32 + s;
  float y[64];
  if (FROMACT) load_act(act1, r, y);
  else         gather_y1(r, xyz, featT, nxyz, ball_idx, W1T, y);
  bnrelu64(y, sc1, sh1);
  float a2[64];
  gemm64<64>(y, W2T, a2);
  bnrelu64(a2, sc2, sh2);
  const int b = pair >> 10, p = pair & (NPOINTS-1);
  float* ob = out + OUT2_OFF + ((size_t)b*128)*1024 + p;
  for (int o=0;o<128;o++){
    const float* wr = W3 + o*64;
    float v = 0.f;
    #pragma unroll
    for (int c=0;c<64;c++) v = fmaf(a2[c], wr[c], v);
    v = fmaxf(0.f, fmaf(v, sc3[o], sh3[o]));
    #pragma unroll
    for (int off=16; off>=1; off>>=1) v = fmaxf(v, __shfl_xor(v, off, 64));
    if (s == 0) ob[(size_t)o*1024] = v;
  }
}

extern "C" void kernel_launch(void* const* d_in, const int* in_sizes, int n_in,
                              void* d_out, int out_size, void* d_ws, size_t ws_size,
                              hipStream_t stream) {
  const float* xyz  = (const float*)d_in[0];
  const float* feat = (const float*)d_in[1];
  const float* W1   = (const float*)d_in[2];
  const float* g1   = (const float*)d_in[3];
  const float* b1   = (const float*)d_in[4];
  const float* W2   = (const float*)d_in[5];
  const float* g2   = (const float*)d_in[6];
  const float* b2   = (const float*)d_in[7];
  const float* W3   = (const float*)d_in[8];
  const float* g3   = (const float*)d_in[9];
  const float* b3   = (const float*)d_in[10];
  float* out = (float*)d_out;
  char* ws = (char*)d_ws;

  // workspace layout
  const size_t o_nxyz = 0;                        // 196608 B
  const size_t o_ball = o_nxyz + 196608;          // 2097152 B
  const size_t o_w1t  = o_ball + 2097152;         // 17408 B
  const size_t o_w2t  = o_w1t  + 17408;           // 16384 B
  const size_t o_w3t  = o_w2t  + 16384;           // 32768 B
  const size_t o_w1p  = o_w3t  + 32768;           // 16384 B
  const size_t o_w2p  = o_w1p  + 16384;           // 16384 B
  const size_t o_w3p  = o_w2p  + 16384;           // 32768 B
  const size_t o_bn   = o_w3p  + 32768;           // 3072 B
  const size_t o_sum  = o_bn   + 3072;            // 2048 B sums + 64 B counters
  const size_t o_ft   = o_sum  + 2112;            // 8 MiB bf16
  const size_t o_mm   = o_ft   + (size_t)16*NN*64*2;   // ymax/ymin 2x8 MiB
  const size_t o_act1 = o_mm   + (size_t)2*128*NPAIRS*4;
  const size_t SZ_A64 = (size_t)MROWS*64*2;       // 64 MiB
  const size_t NEED1  = o_act1 + SZ_A64;          // ~90 MiB
  const size_t o_act2 = o_act1 + SZ_A64;
  const size_t NEED2  = o_act2 + SZ_A64;          // ~155 MiB

  float* nxyz   = (float*)(ws + o_nxyz);
  int*   ball   = (int*)  (ws + o_ball);
  float* W1T    = (float*)(ws + o_w1t);
  float* W2T    = (float*)(ws + o_w2t);
  float* W3T    = (float*)(ws + o_w3t);
  unsigned short* w1p = (unsigned short*)(ws + o_w1p);
  unsigned short* w2p = (unsigned short*)(ws + o_w2p);
  unsigned short* w3p = (unsigned short*)(ws + o_w3p);
  float* sc1    = (float*)(ws + o_bn);
  float* sh1    = (float*)(ws + o_bn + 512);
  float* sc2    = (float*)(ws + o_bn + 1024);
  float* sh2    = (float*)(ws + o_bn + 1536);
  float* sc3    = (float*)(ws + o_bn + 2048);
  float* sh3    = (float*)(ws + o_bn + 2560);
  float* sums1  = (float*)(ws + o_sum);
  float* sums2  = (float*)(ws + o_sum + 512);
  float* sums3  = (float*)(ws + o_sum + 1024);
  unsigned int* cnt1 = (unsigned int*)(ws + o_sum + 2048);
  unsigned int* cnt2 = (unsigned int*)(ws + o_sum + 2052);
  unsigned int* cnt3 = (unsigned int*)(ws + o_sum + 2056);
  unsigned short* featT = (unsigned short*)(ws + o_ft);
  float* ymax   = (float*)(ws + o_mm);
  float* ymin   = (float*)(ws + o_mm + (size_t)128*NPAIRS*4);
  unsigned short* act1  = (unsigned short*)(ws + o_act1);
  unsigned short* act2  = (unsigned short*)(ws + o_act2);

  const int tier = (ws_size >= NEED2) ? 2 : (ws_size >= NEED1) ? 1 : 0;

  hipMemsetAsync(ws + o_sum, 0, 2112, stream);

  k_fps<<<16, 512, 0, stream>>>(xyz, nxyz, out);
  // fused featT + weight-packs + ball query (all throughput-bound, overlap freely)
  k_pb <<<1056 + 4096, 256, 0, stream>>>(xyz, nxyz, ball, feat, featT,
                                         W1, W2, W3, W1T, W2T, W3T, w1p, w2p, w3p);

  if (tier == 2){
    // stage1 (MFMA): gather -> y1, store act1, stats1 + fin1 (last block)
    k_mg1<<<MROWS/256, 256, 0, stream>>>(xyz, featT, nxyz, ball, w1p, W1T, act1, sums1,
                                         cnt1, g1, b1, sc1, sh1);
    // stage2 (MFMA): act1 -> bn1 -> y2, store act2, stats2 + fin2
    k_mgemm<64,false><<<MROWS/256, 256, 0, stream>>>(act1, act2, w2p, sc1, sh1, sums2,
                                                     nullptr, nullptr, cnt2, g2, b2, sc2, sh2);
    // stage3 (MFMA): act2 -> bn2 -> y3, per-(pair,ch) min/max, stats3 + fin3
    k_mgemm<128,true><<<MROWS/256, 256, 0, stream>>>(act2, nullptr, w3p, sc2, sh2, sums3,
                                                     ymax, ymin, cnt3, g3, b3, sc3, sh3);
    k_mx<<<(16*128*1024)/256, 256, 0, stream>>>(ymax, ymin, sc3, sh3, out);
  } else if (tier == 1){
    k_stage<1,0,true><<<NBLK, 64, 0, stream>>>(xyz, featT, nxyz, ball, nullptr, act1,
                                               W1T, W2T, W3T, sc1, sh1, sc2, sh2, sums1);
    k_fin<64><<<1, 64, 0, stream>>>(sums1, g1, b1, sc1, sh1);
    k_stage<2,1,false><<<NBLK, 64, 0, stream>>>(xyz, featT, nxyz, ball, act1, nullptr,
                                                W1T, W2T, W3T, sc1, sh1, sc2, sh2, sums2);
    k_fin<64><<<1, 64, 0, stream>>>(sums2, g2, b2, sc2, sh2);
    k_stage<3,1,false><<<NBLK, 64, 0, stream>>>(xyz, featT, nxyz, ball, act1, nullptr,
                                                W1T, W2T, W3T, sc1, sh1, sc2, sh2, sums3);
    k_fin<128><<<1, 128, 0, stream>>>(sums3, g3, b3, sc3, sh3);
    k_pass2<true><<<8192, 64, 0, stream>>>(xyz, featT, nxyz, ball, act1, W1T, W2T, W3,
                                           sc1, sh1, sc2, sh2, sc3, sh3, out);
  } else {
    k_stage<1,0,false><<<NBLK, 64, 0, stream>>>(xyz, featT, nxyz, ball, nullptr, nullptr,
                                                W1T, W2T, W3T, sc1, sh1, sc2, sh2, sums1);
    k_fin<64><<<1, 64, 0, stream>>>(sums1, g1, b1, sc1, sh1);
    k_stage<2,0,false><<<NBLK, 64, 0, stream>>>(xyz, featT, nxyz, ball, nullptr, nullptr,
                                                W1T, W2T, W3T, sc1, sh1, sc2, sh2, sums2);
    k_fin<64><<<1, 64, 0, stream>>>(sums2, g2, b2, sc2, sh2);
    k_stage<3,0,false><<<NBLK, 64, 0, stream>>>(xyz, featT, nxyz, ball, nullptr, nullptr,
                                                W1T, W2T, W3T, sc1, sh1, sc2, sh2, sums3);
    k_fin<128><<<1, 128, 0, stream>>>(sums3, g3, b3, sc3, sh3);
    k_pass2<false><<<8192, 64, 0, stream>>>(xyz, featT, nxyz, ball, nullptr, W1T, W2T, W3,
                                            sc1, sh1, sc2, sh2, sc3, sh3, out);
  }
}

// Round 12
// 985.427 us; speedup vs baseline: 1.7435x; 1.7435x over previous
//
#include <hip/hip_runtime.h>

#define NN 4096
#define NPOINTS 1024
#define NSAMP 32
#define MROWS (16*NPOINTS*NSAMP)      // 524288
#define NPAIRS (MROWS/32)             // 16384
#define OUT2_OFF (16*NPOINTS*3)       // 49152
#define EPSF 1e-5f
#define RPB 128                       // rows per stats block (legacy k_stage)
#define NBLK 4096                     // legacy stats blocks

typedef unsigned long long ull;
using f32x4  = __attribute__((ext_vector_type(4))) float;
using bf16x8 = __attribute__((ext_vector_type(8))) short;

// ---------- bf16 helpers ----------
__device__ __forceinline__ float bflo(unsigned int u){ union{unsigned int i; float f;} v; v.i = u << 16; return v.f; }
__device__ __forceinline__ float bfhi(unsigned int u){ union{unsigned int i; float f;} v; v.i = u & 0xffff0000u; return v.f; }
__device__ __forceinline__ unsigned short f2bf(float f){
  union{float f; unsigned int i;} v; v.f = f;
  unsigned int r = v.i + 0x7fffu + ((v.i >> 16) & 1u);
  return (unsigned short)(r >> 16);
}

__device__ __forceinline__ unsigned short packhl(float v, int isLo){
  unsigned short h = f2bf(v);
  if (isLo){ float r = __fsub_rn(v, bflo((unsigned)h)); h = f2bf(r); }
  return h;
}

// ---------- FPS: r3/r9 version, measured 665 us (parked at structural floor) ----------
__global__ __launch_bounds__(512) void k_fps(const float* __restrict__ xyz,
    float* __restrict__ nxyz, float* __restrict__ out){
  __shared__ float xs[NN], ys[NN], zs[NN];
  __shared__ ull wbest[2][8];
  const int b = blockIdx.x, t = threadIdx.x;
  const float* xb = xyz + (size_t)b*NN*3;
  for (int j = t; j < NN; j += 512){
    xs[j] = xb[j*3+0]; ys[j] = xb[j*3+1]; zs[j] = xb[j*3+2];
  }
  __syncthreads();
  float px[8], py[8], pz[8], pd[8];
  #pragma unroll
  for (int j=0;j<8;j++){ int i=j*512+t; px[j]=xs[i]; py[j]=ys[i]; pz[j]=zs[i]; pd[j]=1e10f; }
  int cur = 0;
  const int lane = t & 63, wv = t >> 6;
  for (int it=0; it<NPOINTS; ++it){
    float lx = xs[cur], ly = ys[cur], lz = zs[cur];
    if (t == 0){
      int o = (b*NPOINTS + it)*3;
      nxyz[o]=lx; nxyz[o+1]=ly; nxyz[o+2]=lz;
      out[o]=lx;  out[o+1]=ly;  out[o+2]=lz;
    }
    float bv = -1.0f; int bi = 0;
    #pragma unroll
    for (int j=0;j<8;j++){
      float dx = __fsub_rn(px[j], lx);
      float dy = __fsub_rn(py[j], ly);
      float dz = __fsub_rn(pz[j], lz);
      float d  = __fadd_rn(__fadd_rn(__fmul_rn(dx,dx), __fmul_rn(dy,dy)), __fmul_rn(dz,dz));
      float nd = fminf(pd[j], d);
      pd[j] = nd;
      if (nd > bv){ bv = nd; bi = j*512 + t; }
    }
    ull key = ((ull)__float_as_uint(bv) << 32) | (ull)(0xFFFFFFFFu - (unsigned)bi);
    #define DPPSTEP(ctrl, rmask) { \
      unsigned int tlo = __builtin_amdgcn_update_dpp(0, (int)(unsigned int)(key & 0xFFFFFFFFull), ctrl, rmask, 0xf, false); \
      unsigned int thi = __builtin_amdgcn_update_dpp(0, (int)(unsigned int)(key >> 32), ctrl, rmask, 0xf, false); \
      ull tk = ((ull)thi << 32) | (ull)tlo; \
      if (tk > key) key = tk; }
    DPPSTEP(0x111, 0xf)
    DPPSTEP(0x112, 0xf)
    DPPSTEP(0x114, 0xf)
    DPPSTEP(0x118, 0xf)
    DPPSTEP(0x142, 0xa)
    DPPSTEP(0x143, 0xc)
    #undef DPPSTEP
    if (lane == 63) wbest[it & 1][wv] = key;
    __syncthreads();
    ull best = wbest[it & 1][0];
    #pragma unroll
    for (int w=1; w<8; w++){
      ull ok = wbest[it & 1][w];
      if (ok > best) best = ok;
    }
    cur = (int)(0xFFFFFFFFu - (unsigned)(best & 0xFFFFFFFFull));
  }
}

// ---------- fused post-FPS pre-pass: featT (blocks 0..1023) + weight packs
// (1024..1055) + ball query (1056..5151). All throughput-bound, 256 thr. ----------
__global__ __launch_bounds__(256) void k_pb(
    const float* __restrict__ xyz, const float* __restrict__ nxyz, int* __restrict__ ball_idx,
    const float* __restrict__ feat, unsigned short* __restrict__ featT,
    const float* __restrict__ W1, const float* __restrict__ W2, const float* __restrict__ W3,
    float* __restrict__ W1T, float* __restrict__ W2T, float* __restrict__ W3T,
    unsigned short* __restrict__ w1p, unsigned short* __restrict__ w2p, unsigned short* __restrict__ w3p)
{
  __shared__ float tile[64*65];
  const int bid = blockIdx.x;
  const int t = threadIdx.x;
  if (bid < 1024){
    // ---- featT: (B,64,N) fp32 -> (B,N,64) bf16 (exact k_ft) ----
    const int b = bid >> 6, n0 = (bid & 63) << 6;
    const int nl = t & 63, cb = t >> 6;
    #pragma unroll
    for (int k=0;k<16;k++){
      int c = cb + (k<<2);
      tile[c*65 + nl] = feat[((size_t)(b*64 + c))*NN + n0 + nl];
    }
    __syncthreads();
    #pragma unroll
    for (int k=0;k<16;k++){
      int nl2 = cb + (k<<2);
      featT[((size_t)(b*NN) + n0 + nl2)*64 + nl] = f2bf(tile[nl*65 + nl2]);
    }
  } else if (bid < 1056){
    // ---- weight transposes + MFMA B-fragment packs (exact k_wt) ----
    int g = (bid - 1024)*256 + t;            // 0..8191
    if (g < 67*64){ int c = g >> 6, o = g & 63;  W1T[g] = W1[o*67 + c]; }
    if (g < 64*64){ int c = g >> 6, o = g & 63;  W2T[g] = W2[o*64 + c]; }
    if (g < 64*128){ int c = g >> 7, o = g & 127; W3T[g] = W3[o*64 + c]; }
    if (g < 1024){   // W1 feat part (cols 3..66): NTG=4 -> 16 frags
      int f=g>>6, l=g&63, isLo=f>>3, f0=f&7, kf=f0>>2, ntg=f0&3;
      const float* src = W1 + (ntg*16+(l&15))*67 + 3 + kf*32 + ((l>>4)*8);
      unsigned short* dst = w1p + ((size_t)f*64 + l)*8;
      #pragma unroll
      for (int j=0;j<8;j++) dst[j] = packhl(src[j], isLo);
    }
    if (g < 1024){   // W2
      int f=g>>6, l=g&63, isLo=f>>3, f0=f&7, kf=f0>>2, ntg=f0&3;
      const float* src = W2 + (ntg*16+(l&15))*64 + kf*32 + ((l>>4)*8);
      unsigned short* dst = w2p + ((size_t)f*64 + l)*8;
      #pragma unroll
      for (int j=0;j<8;j++) dst[j] = packhl(src[j], isLo);
    }
    if (g < 2048){   // W3
      int f=g>>6, l=g&63, isLo=f>>4, f0=f&15, kf=f0>>3, ntg=f0&7;
      const float* src = W3 + (ntg*16+(l&15))*64 + kf*32 + ((l>>4)*8);
      unsigned short* dst = w3p + ((size_t)f*64 + l)*8;
      #pragma unroll
      for (int j=0;j<8;j++) dst[j] = packhl(src[j], isLo);
    }
  } else {
    // ---- ball query: wave-per-query, ballot/prefix first-32 (exact r9 k_ball) ----
    const int lane = t & 63;
    const int q = (bid - 1056)*4 + (t >> 6);  // 16384 queries
    const int b = q >> 10;
    const float* xb = xyz + (size_t)b*NN*3;
    const int co = q*3;
    const float cx = nxyz[co], cy = nxyz[co+1], cz = nxyz[co+2];
    const int base = q*NSAMP;
    const float R2 = 0.04f;
    int cnt = 0, first = 0;
    for (int i0 = 0; i0 < NN; i0 += 64){
      const int i = i0 + lane;
      float lx = xb[i*3+0], ly = xb[i*3+1], lz = xb[i*3+2];
      float dx = __fsub_rn(cx, lx);
      float dy = __fsub_rn(cy, ly);
      float dz = __fsub_rn(cz, lz);
      float d2 = __fadd_rn(__fadd_rn(__fmul_rn(dx,dx), __fmul_rn(dy,dy)), __fmul_rn(dz,dz));
      const bool in = (d2 < R2);
      ull mask = __ballot(in);
      if (mask){
        if (cnt == 0) first = i0 + (int)__ffsll((long long)mask) - 1;
        int slot = cnt + (int)__popcll(mask & ((1ull << lane) - 1ull));
        if (in && slot < NSAMP) ball_idx[base + slot] = i;
        cnt += (int)__popcll(mask);
        if (cnt >= NSAMP) break;
      }
    }
    if (lane >= cnt && lane < NSAMP) ball_idx[base + lane] = first;
  }
}

// ---------- row producers (legacy fallback path) ----------
__device__ __forceinline__ void gather_y1(int r,
    const float* __restrict__ xyz, const unsigned short* __restrict__ featT,
    const float* __restrict__ nxyz, const int* __restrict__ ball_idx,
    const float* __restrict__ W1T, float* __restrict__ y)
{
  const int b = r >> 15;
  const int p = (r >> 5) & (NPOINTS-1);
  const int i = ball_idx[r];
  const int co = (b*NPOINTS + p)*3;
  const float* xp = xyz + ((size_t)(b*NN + i))*3;
  const float h0 = __fsub_rn(xp[0], nxyz[co]);
  const float h1 = __fsub_rn(xp[1], nxyz[co+1]);
  const float h2 = __fsub_rn(xp[2], nxyz[co+2]);
  #pragma unroll
  for (int o=0;o<64;o++) y[o] = h0 * W1T[o];
  #pragma unroll
  for (int o=0;o<64;o++) y[o] = fmaf(h1, W1T[64+o], y[o]);
  #pragma unroll
  for (int o=0;o<64;o++) y[o] = fmaf(h2, W1T[128+o], y[o]);
  const uint4* fp = (const uint4*)(featT + ((size_t)(b*NN + i))*64);
  #pragma unroll
  for (int c8=0;c8<8;c8++){
    const uint4 u = fp[c8];
    float fv[8];
    fv[0]=bflo(u.x); fv[1]=bfhi(u.x); fv[2]=bflo(u.y); fv[3]=bfhi(u.y);
    fv[4]=bflo(u.z); fv[5]=bfhi(u.z); fv[6]=bflo(u.w); fv[7]=bfhi(u.w);
    const float* wb = W1T + (3 + c8*8)*64;
    #pragma unroll
    for (int k=0;k<8;k++){
      #pragma unroll
      for (int o=0;o<64;o++) y[o] = fmaf(fv[k], wb[k*64+o], y[o]);
    }
  }
}

__device__ __forceinline__ void load_act(const unsigned short* __restrict__ act, int r, float* __restrict__ y){
  const uint4* p = (const uint4*)(act + (size_t)r*64);
  #pragma unroll
  for (int j=0;j<8;j++){
    uint4 u = p[j];
    y[j*8+0]=bflo(u.x); y[j*8+1]=bfhi(u.x); y[j*8+2]=bflo(u.y); y[j*8+3]=bfhi(u.y);
    y[j*8+4]=bflo(u.z); y[j*8+5]=bfhi(u.z); y[j*8+6]=bflo(u.w); y[j*8+7]=bfhi(u.w);
  }
}

__device__ __forceinline__ void store_bf16x64(unsigned short* __restrict__ dst, const float* __restrict__ y){
  uint4* row = (uint4*)dst;
  #pragma unroll
  for (int j=0;j<8;j++){
    union { uint4 u; unsigned short h[8]; } pk;
    #pragma unroll
    for (int k=0;k<8;k++) pk.h[k] = f2bf(y[j*8+k]);
    row[j] = pk.u;
  }
}

__device__ __forceinline__ void bnrelu64(float* __restrict__ y,
    const float* __restrict__ sc, const float* __restrict__ sh){
  #pragma unroll
  for (int o=0;o<64;o++) y[o] = fmaxf(0.f, fmaf(y[o], sc[o], sh[o]));
}

template<int LDW>
__device__ __forceinline__ void gemm64(const float* __restrict__ a, const float* __restrict__ WT,
                                       float* __restrict__ out){
  #pragma unroll
  for (int o=0;o<64;o++) out[o] = 0.f;
  #pragma unroll 4
  for (int c=0;c<64;c++){
    const float av = a[c];
    const float* wb = WT + c*LDW;
    #pragma unroll
    for (int o=0;o<64;o++) out[o] = fmaf(av, wb[o], out[o]);
  }
}

__device__ __forceinline__ void stats_tile(float* tile, int t, const float* __restrict__ y,
                                           float& s, float& q){
  #pragma unroll
  for (int j=0;j<64;j++) tile[t*65 + j] = y[j];
  __syncthreads();
  #pragma unroll 8
  for (int r=0;r<64;r++){
    float v = tile[r*65 + t];
    s += v; q = fmaf(v, v, q);
  }
  __syncthreads();
}

// ---------- legacy fused stage kernels (tier<2 fallback) ----------
template<int STAGE, int SRC, bool STORE>
__global__ __launch_bounds__(64) void k_stage(
    const float* __restrict__ xyz, const unsigned short* __restrict__ featT,
    const float* __restrict__ nxyz, const int* __restrict__ ball_idx,
    const unsigned short* __restrict__ actin, unsigned short* __restrict__ actout,
    const float* __restrict__ W1T, const float* __restrict__ W2T, const float* __restrict__ W3T,
    const float* __restrict__ sc1, const float* __restrict__ sh1,
    const float* __restrict__ sc2, const float* __restrict__ sh2,
    float* __restrict__ sums)
{
  __shared__ float tile[64*65];
  const int t = threadIdx.x;
  float s0=0.f, q0=0.f, s1=0.f, q1=0.f;
  for (int it=0; it<RPB/64; ++it){
    const int r = blockIdx.x*RPB + it*64 + t;
    float y[64];
    if constexpr (SRC == 0) gather_y1(r, xyz, featT, nxyz, ball_idx, W1T, y);
    else                    load_act(actin, r, y);
    if constexpr (STAGE == 1){
      if constexpr (STORE) store_bf16x64(actout + (size_t)r*64, y);
      stats_tile(tile, t, y, s0, q0);
    } else if constexpr (STAGE == 2){
      bnrelu64(y, sc1, sh1);
      float y2[64];
      gemm64<64>(y, W2T, y2);
      if constexpr (STORE) store_bf16x64(actout + (size_t)r*64, y2);
      stats_tile(tile, t, y2, s0, q0);
    } else {
      float a2[64];
      if constexpr (SRC != 2){
        bnrelu64(y, sc1, sh1);
        gemm64<64>(y, W2T, a2);
      } else {
        #pragma unroll
        for (int o=0;o<64;o++) a2[o] = y[o];
      }
      bnrelu64(a2, sc2, sh2);
      float y3[64];
      gemm64<128>(a2, W3T, y3);
      if constexpr (STORE) store_bf16x64(actout + (size_t)r*128, y3);
      stats_tile(tile, t, y3, s0, q0);
      gemm64<128>(a2, W3T + 64, y3);
      if constexpr (STORE) store_bf16x64(actout + (size_t)r*128 + 64, y3);
      stats_tile(tile, t, y3, s1, q1);
    }
  }
  if constexpr (STAGE < 3){
    atomicAdd(&sums[t], s0);
    atomicAdd(&sums[64 + t], q0);
  } else {
    atomicAdd(&sums[t], s0);
    atomicAdd(&sums[64 + t], s1);
    atomicAdd(&sums[128 + t], q0);
    atomicAdd(&sums[192 + t], q1);
  }
}

// ---------- BN finalize (separate launch; r11's device-side fin regressed) ----------
template<int C>
__global__ void k_fin(const float* __restrict__ sums,
    const float* __restrict__ g, const float* __restrict__ bv,
    float* __restrict__ scale, float* __restrict__ shift)
{
  const int c = threadIdx.x;
  float m  = sums[c]   * (1.f/(float)MROWS);
  float vv = sums[C+c] * (1.f/(float)MROWS) - m*m;
  float sc = g[c] / sqrtf(vv + EPSF);
  scale[c] = sc;
  shift[c] = bv[c] - m*sc;
}

// ---------- MFMA stage1: y1 = [h|feat] @ W1^T, store act1, stats1 (exact r9) ----------
__global__ __launch_bounds__(256) void k_mg1(
    const float* __restrict__ xyz, const unsigned short* __restrict__ featT,
    const float* __restrict__ nxyz, const int* __restrict__ ball_idx,
    const unsigned short* __restrict__ w1p, const float* __restrict__ W1T,
    unsigned short* __restrict__ act1, float* __restrict__ sums)
{
  __shared__ float hxs[256], hys[256], hzs[256];
  __shared__ float w1s[192];
  __shared__ float lsum[128];
  const int t = threadIdx.x, lane = t & 63, wv = t >> 6;
  const int blkrow = blockIdx.x*256;
  {  // phase A: one row per thread -> h into LDS
    int r = blkrow + t;
    int b = r >> 15, p = (r >> 5) & (NPOINTS-1), i = ball_idx[r];
    const float* xp = xyz + ((size_t)(b*NN + i))*3;
    int co = (b*NPOINTS + p)*3;
    hxs[t] = __fsub_rn(xp[0], nxyz[co]);
    hys[t] = __fsub_rn(xp[1], nxyz[co+1]);
    hzs[t] = __fsub_rn(xp[2], nxyz[co+2]);
  }
  if (t < 192) w1s[t] = W1T[t];
  if (t < 128) lsum[t] = 0.f;
  __syncthreads();
  const int rowbase = blkrow + wv*64;
  const int kc0 = (lane>>4)*8;
  bf16x8 A[4][2];
  #pragma unroll
  for (int mt=0;mt<4;mt++){
    int r = rowbase + mt*16 + (lane&15);
    int b = r >> 15, i = ball_idx[r];
    const unsigned short* fp = featT + ((size_t)(b*NN + i))*64 + kc0;
    A[mt][0] = *(const bf16x8*)(fp);
    A[mt][1] = *(const bf16x8*)(fp + 32);
  }
  bf16x8 Bh[2][4], Bl[2][4];
  #pragma unroll
  for (int kf=0;kf<2;kf++)
    #pragma unroll
    for (int nt=0;nt<4;nt++){
      Bh[kf][nt] = *(const bf16x8*)(w1p + ((size_t)(kf*4+nt)*64 + lane)*8);
      Bl[kf][nt] = *(const bf16x8*)(w1p + ((size_t)(8 + kf*4+nt)*64 + lane)*8);
    }
  f32x4 c[4][4];
  const int lr0 = wv*64 + (lane>>4)*4;
  #pragma unroll
  for (int nt=0;nt<4;nt++){
    int col = nt*16 + (lane&15);
    float w0 = w1s[col], w1 = w1s[64+col], w2 = w1s[128+col];
    #pragma unroll
    for (int mt=0;mt<4;mt++)
      #pragma unroll
      for (int rr=0;rr<4;rr++){
        int lr = lr0 + mt*16 + rr;
        c[mt][nt][rr] = fmaf(hzs[lr], w2, fmaf(hys[lr], w1, hxs[lr]*w0));
      }
  }
  #pragma unroll
  for (int mt=0;mt<4;mt++)
    #pragma unroll
    for (int nt=0;nt<4;nt++){
      f32x4 acc = c[mt][nt];
      acc = __builtin_amdgcn_mfma_f32_16x16x32_bf16(A[mt][0], Bh[0][nt], acc, 0,0,0);
      acc = __builtin_amdgcn_mfma_f32_16x16x32_bf16(A[mt][1], Bh[1][nt], acc, 0,0,0);
      acc = __builtin_amdgcn_mfma_f32_16x16x32_bf16(A[mt][0], Bl[0][nt], acc, 0,0,0);
      acc = __builtin_amdgcn_mfma_f32_16x16x32_bf16(A[mt][1], Bl[1][nt], acc, 0,0,0);
      c[mt][nt] = acc;
    }
  #pragma unroll
  for (int nt=0;nt<4;nt++){
    float s=0.f, q=0.f;
    #pragma unroll
    for (int mt=0;mt<4;mt++)
      #pragma unroll
      for (int rr=0;rr<4;rr++){ float v=c[mt][nt][rr]; s+=v; q=fmaf(v,v,q); }
    s += __shfl_xor(s,16,64); s += __shfl_xor(s,32,64);
    q += __shfl_xor(q,16,64); q += __shfl_xor(q,32,64);
    if (lane<16){
      atomicAdd(&lsum[nt*16+lane], s);
      atomicAdd(&lsum[64 + nt*16+lane], q);
    }
  }
  #pragma unroll
  for (int nt=0;nt<4;nt++)
    #pragma unroll
    for (int mt=0;mt<4;mt++)
      #pragma unroll
      for (int rr=0;rr<4;rr++){
        int row = rowbase + mt*16 + (lane>>4)*4 + rr;
        act1[(size_t)row*64 + nt*16 + (lane&15)] = f2bf(c[mt][nt][rr]);
      }
  __syncthreads();
  if (t < 128) atomicAdd(&sums[t], lsum[t]);
}

// ---------- MFMA stage GEMM: y = bnrelu(actin) @ W^T (exact r9) ----------
__device__ __forceinline__ bf16x8 ldA_bn(const unsigned short* __restrict__ p,
    const float* __restrict__ sc, const float* __restrict__ sh){
  uint4 u = *(const uint4*)p;
  unsigned w[4] = {u.x, u.y, u.z, u.w};
  union { bf16x8 v; unsigned short h[8]; } o;
  #pragma unroll
  for (int q=0;q<4;q++){
    float lo = fmaxf(0.f, fmaf(bflo(w[q]), sc[2*q],   sh[2*q]));
    float hi = fmaxf(0.f, fmaf(bfhi(w[q]), sc[2*q+1], sh[2*q+1]));
    o.h[2*q]   = f2bf(lo);
    o.h[2*q+1] = f2bf(hi);
  }
  return o.v;
}

template<int NOUT, bool MINMAX>
__global__ __launch_bounds__(256) void k_mgemm(
    const unsigned short* __restrict__ actin,
    unsigned short* __restrict__ actout,
    const unsigned short* __restrict__ wp,
    const float* __restrict__ scp, const float* __restrict__ shp,
    float* __restrict__ sums,
    float* __restrict__ ymax, float* __restrict__ ymin)
{
  constexpr int NTG = NOUT/16;
  __shared__ float lsum[2*NOUT];
  const int t = threadIdx.x, lane = t & 63, wv = t >> 6;
  for (int i=t;i<2*NOUT;i+=256) lsum[i]=0.f;
  __syncthreads();
  const int rowbase = blockIdx.x*256 + wv*64;
  const int kc0 = (lane>>4)*8;
  float scl[16], shl[16];
  #pragma unroll
  for (int kf=0;kf<2;kf++)
    #pragma unroll
    for (int j=0;j<8;j++){
      scl[kf*8+j] = scp[kf*32+kc0+j];
      shl[kf*8+j] = shp[kf*32+kc0+j];
    }
  bf16x8 A[4][2];
  #pragma unroll
  for (int mt=0;mt<4;mt++)
    #pragma unroll
    for (int kf=0;kf<2;kf++)
      A[mt][kf] = ldA_bn(actin + ((size_t)(rowbase + mt*16 + (lane&15)))*64 + kf*32 + kc0,
                         &scl[kf*8], &shl[kf*8]);
  #pragma unroll
  for (int h=0; h<NOUT/64; h++){
    bf16x8 Bh[2][4], Bl[2][4];
    #pragma unroll
    for (int kf=0;kf<2;kf++)
      #pragma unroll
      for (int nt=0;nt<4;nt++){
        int ntg = h*4+nt;
        Bh[kf][nt] = *(const bf16x8*)(wp + ((size_t)(kf*NTG+ntg)*64 + lane)*8);
        Bl[kf][nt] = *(const bf16x8*)(wp + ((size_t)(2*NTG + kf*NTG+ntg)*64 + lane)*8);
      }
    f32x4 c[4][4];
    #pragma unroll
    for (int mt=0;mt<4;mt++)
      #pragma unroll
      for (int nt=0;nt<4;nt++){
        f32x4 acc = {0.f,0.f,0.f,0.f};
        acc = __builtin_amdgcn_mfma_f32_16x16x32_bf16(A[mt][0], Bh[0][nt], acc, 0,0,0);
        acc = __builtin_amdgcn_mfma_f32_16x16x32_bf16(A[mt][1], Bh[1][nt], acc, 0,0,0);
        acc = __builtin_amdgcn_mfma_f32_16x16x32_bf16(A[mt][0], Bl[0][nt], acc, 0,0,0);
        acc = __builtin_amdgcn_mfma_f32_16x16x32_bf16(A[mt][1], Bl[1][nt], acc, 0,0,0);
        c[mt][nt] = acc;
      }
    #pragma unroll
    for (int nt=0;nt<4;nt++){
      float s=0.f, q=0.f;
      #pragma unroll
      for (int mt=0;mt<4;mt++)
        #pragma unroll
        for (int r=0;r<4;r++){ float v=c[mt][nt][r]; s+=v; q=fmaf(v,v,q); }
      s += __shfl_xor(s,16,64); s += __shfl_xor(s,32,64);
      q += __shfl_xor(q,16,64); q += __shfl_xor(q,32,64);
      if (lane<16){
        atomicAdd(&lsum[h*64+nt*16+lane], s);
        atomicAdd(&lsum[NOUT + h*64+nt*16+lane], q);
      }
    }
    if constexpr (!MINMAX){
      #pragma unroll
      for (int nt=0;nt<4;nt++)
        #pragma unroll
        for (int mt=0;mt<4;mt++)
          #pragma unroll
          for (int r=0;r<4;r++){
            int row = rowbase + mt*16 + (lane>>4)*4 + r;
            actout[(size_t)row*NOUT + h*64 + nt*16 + (lane&15)] = f2bf(c[mt][nt][r]);
          }
    } else {
      #pragma unroll
      for (int nt=0;nt<4;nt++){
        float mx0=-1e30f, mn0=1e30f, mx1=-1e30f, mn1=1e30f;
        #pragma unroll
        for (int mt=0;mt<2;mt++)
          #pragma unroll
          for (int r=0;r<4;r++){ float v=c[mt][nt][r]; mx0=fmaxf(mx0,v); mn0=fminf(mn0,v); }
        #pragma unroll
        for (int mt=2;mt<4;mt++)
          #pragma unroll
          for (int r=0;r<4;r++){ float v=c[mt][nt][r]; mx1=fmaxf(mx1,v); mn1=fminf(mn1,v); }
        mx0=fmaxf(mx0,__shfl_xor(mx0,16,64)); mx0=fmaxf(mx0,__shfl_xor(mx0,32,64));
        mn0=fminf(mn0,__shfl_xor(mn0,16,64)); mn0=fminf(mn0,__shfl_xor(mn0,32,64));
        mx1=fmaxf(mx1,__shfl_xor(mx1,16,64)); mx1=fmaxf(mx1,__shfl_xor(mx1,32,64));
        mn1=fminf(mn1,__shfl_xor(mn1,16,64)); mn1=fminf(mn1,__shfl_xor(mn1,32,64));
        if (lane<16){
          int ch = h*64+nt*16+lane;
          int pair0 = rowbase>>5;
          float2 vx = {mx0, mx1}, vn = {mn0, mn1};
          *(float2*)(ymax + (size_t)ch*NPAIRS + pair0) = vx;
          *(float2*)(ymin + (size_t)ch*NPAIRS + pair0) = vn;
        }
      }
    }
  }
  __syncthreads();
  for (int i=t;i<2*NOUT;i+=256) atomicAdd(&sums[i], lsum[i]);
}

// ---------- tier2 final: bn3+relu applied to per-(pair,ch) extremum ----------
__global__ __launch_bounds__(256) void k_mx(const float* __restrict__ ymax,
    const float* __restrict__ ymin, const float* __restrict__ sc3,
    const float* __restrict__ sh3, float* __restrict__ out){
  int idx = blockIdx.x*256 + threadIdx.x;     // 16*128*1024
  int p = idx & 1023;
  int o = (idx>>10) & 127;
  int b = idx>>17;
  float sc = sc3[o], sh = sh3[o];
  size_t src = (size_t)o*NPAIRS + b*1024 + p;
  float v = (sc >= 0.f) ? ymax[src] : ymin[src];
  out[OUT2_OFF + ((size_t)(b*128+o))*1024 + p] = fmaxf(0.f, fmaf(v, sc, sh));
}

// ---------- fallback final pass (tier<2) ----------
template<bool FROMACT>
__global__ __launch_bounds__(64) void k_pass2(
    const float* __restrict__ xyz, const unsigned short* __restrict__ featT,
    const float* __restrict__ nxyz, const int* __restrict__ ball_idx,
    const unsigned short* __restrict__ act1,
    const float* __restrict__ W1T, const float* __restrict__ W2T,
    const float* __restrict__ W3,
    const float* __restrict__ sc1, const float* __restrict__ sh1,
    const float* __restrict__ sc2, const float* __restrict__ sh2,
    const float* __restrict__ sc3, const float* __restrict__ sh3,
    float* __restrict__ out)
{
  const int t = threadIdx.x;
  const int s = t & 31;
  const int pair = blockIdx.x*2 + (t >> 5);
  const int r = pair*32 + s;
  float y[64];
  if (FROMACT) load_act(act1, r, y);
  else         gather_y1(r, xyz, featT, nxyz, ball_idx, W1T, y);
  bnrelu64(y, sc1, sh1);
  float a2[64];
  gemm64<64>(y, W2T, a2);
  bnrelu64(a2, sc2, sh2);
  const int b = pair >> 10, p = pair & (NPOINTS-1);
  float* ob = out + OUT2_OFF + ((size_t)b*128)*1024 + p;
  for (int o=0;o<128;o++){
    const float* wr = W3 + o*64;
    float v = 0.f;
    #pragma unroll
    for (int c=0;c<64;c++) v = fmaf(a2[c], wr[c], v);
    v = fmaxf(0.f, fmaf(v, sc3[o], sh3[o]));
    #pragma unroll
    for (int off=16; off>=1; off>>=1) v = fmaxf(v, __shfl_xor(v, off, 64));
    if (s == 0) ob[(size_t)o*1024] = v;
  }
}

extern "C" void kernel_launch(void* const* d_in, const int* in_sizes, int n_in,
                              void* d_out, int out_size, void* d_ws, size_t ws_size,
                              hipStream_t stream) {
  const float* xyz  = (const float*)d_in[0];
  const float* feat = (const float*)d_in[1];
  const float* W1   = (const float*)d_in[2];
  const float* g1   = (const float*)d_in[3];
  const float* b1   = (const float*)d_in[4];
  const float* W2   = (const float*)d_in[5];
  const float* g2   = (const float*)d_in[6];
  const float* b2   = (const float*)d_in[7];
  const float* W3   = (const float*)d_in[8];
  const float* g3   = (const float*)d_in[9];
  const float* b3   = (const float*)d_in[10];
  float* out = (float*)d_out;
  char* ws = (char*)d_ws;

  // workspace layout
  const size_t o_nxyz = 0;                        // 196608 B
  const size_t o_ball = o_nxyz + 196608;          // 2097152 B
  const size_t o_w1t  = o_ball + 2097152;         // 17408 B
  const size_t o_w2t  = o_w1t  + 17408;           // 16384 B
  const size_t o_w3t  = o_w2t  + 16384;           // 32768 B
  const size_t o_w1p  = o_w3t  + 32768;           // 16384 B
  const size_t o_w2p  = o_w1p  + 16384;           // 16384 B
  const size_t o_w3p  = o_w2p  + 16384;           // 32768 B
  const size_t o_bn   = o_w3p  + 32768;           // 3072 B
  const size_t o_sum  = o_bn   + 3072;            // 2048 B
  const size_t o_ft   = o_sum  + 2048;            // 8 MiB bf16
  const size_t o_mm   = o_ft   + (size_t)16*NN*64*2;   // ymax/ymin 2x8 MiB
  const size_t o_act1 = o_mm   + (size_t)2*128*NPAIRS*4;
  const size_t SZ_A64 = (size_t)MROWS*64*2;       // 64 MiB
  const size_t NEED1  = o_act1 + SZ_A64;          // ~90 MiB
  const size_t o_act2 = o_act1 + SZ_A64;
  const size_t NEED2  = o_act2 + SZ_A64;          // ~155 MiB

  float* nxyz   = (float*)(ws + o_nxyz);
  int*   ball   = (int*)  (ws + o_ball);
  float* W1T    = (float*)(ws + o_w1t);
  float* W2T    = (float*)(ws + o_w2t);
  float* W3T    = (float*)(ws + o_w3t);
  unsigned short* w1p = (unsigned short*)(ws + o_w1p);
  unsigned short* w2p = (unsigned short*)(ws + o_w2p);
  unsigned short* w3p = (unsigned short*)(ws + o_w3p);
  float* sc1    = (float*)(ws + o_bn);
  float* sh1    = (float*)(ws + o_bn + 512);
  float* sc2    = (float*)(ws + o_bn + 1024);
  float* sh2    = (float*)(ws + o_bn + 1536);
  float* sc3    = (float*)(ws + o_bn + 2048);
  float* sh3    = (float*)(ws + o_bn + 2560);
  float* sums1  = (float*)(ws + o_sum);
  float* sums2  = (float*)(ws + o_sum + 512);
  float* sums3  = (float*)(ws + o_sum + 1024);
  unsigned short* featT = (unsigned short*)(ws + o_ft);
  float* ymax   = (float*)(ws + o_mm);
  float* ymin   = (float*)(ws + o_mm + (size_t)128*NPAIRS*4);
  unsigned short* act1  = (unsigned short*)(ws + o_act1);
  unsigned short* act2  = (unsigned short*)(ws + o_act2);

  const int tier = (ws_size >= NEED2) ? 2 : (ws_size >= NEED1) ? 1 : 0;

  hipMemsetAsync(ws + o_sum, 0, 2048, stream);

  k_fps<<<16, 512, 0, stream>>>(xyz, nxyz, out);
  // fused featT + weight-packs + ball query (throughput-bound; kept from r11)
  k_pb <<<1056 + 4096, 256, 0, stream>>>(xyz, nxyz, ball, feat, featT,
                                         W1, W2, W3, W1T, W2T, W3T, w1p, w2p, w3p);

  if (tier == 2){
    // stage1 (MFMA): gather -> y1, store act1, stats1
    k_mg1<<<MROWS/256, 256, 0, stream>>>(xyz, featT, nxyz, ball, w1p, W1T, act1, sums1);
    k_fin<64><<<1, 64, 0, stream>>>(sums1, g1, b1, sc1, sh1);
    // stage2 (MFMA): act1 -> bn1 -> y2, store act2, stats2
    k_mgemm<64,false><<<MROWS/256, 256, 0, stream>>>(act1, act2, w2p, sc1, sh1, sums2,
                                                     nullptr, nullptr);
    k_fin<64><<<1, 64, 0, stream>>>(sums2, g2, b2, sc2, sh2);
    // stage3 (MFMA): act2 -> bn2 -> y3, per-(pair,ch) min/max, stats3
    k_mgemm<128,true><<<MROWS/256, 256, 0, stream>>>(act2, nullptr, w3p, sc2, sh2, sums3,
                                                     ymax, ymin);
    k_fin<128><<<1, 128, 0, stream>>>(sums3, g3, b3, sc3, sh3);
    k_mx<<<(16*128*1024)/256, 256, 0, stream>>>(ymax, ymin, sc3, sh3, out);
  } else if (tier == 1){
    k_stage<1,0,true><<<NBLK, 64, 0, stream>>>(xyz, featT, nxyz, ball, nullptr, act1,
                                               W1T, W2T, W3T, sc1, sh1, sc2, sh2, sums1);
    k_fin<64><<<1, 64, 0, stream>>>(sums1, g1, b1, sc1, sh1);
    k_stage<2,1,false><<<NBLK, 64, 0, stream>>>(xyz, featT, nxyz, ball, act1, nullptr,
                                                W1T, W2T, W3T, sc1, sh1, sc2, sh2, sums2);
    k_fin<64><<<1, 64, 0, stream>>>(sums2, g2, b2, sc2, sh2);
    k_stage<3,1,false><<<NBLK, 64, 0, stream>>>(xyz, featT, nxyz, ball, act1, nullptr,
                                                W1T, W2T, W3T, sc1, sh1, sc2, sh2, sums3);
    k_fin<128><<<1, 128, 0, stream>>>(sums3, g3, b3, sc3, sh3);
    k_pass2<true><<<8192, 64, 0, stream>>>(xyz, featT, nxyz, ball, act1, W1T, W2T, W3,
                                           sc1, sh1, sc2, sh2, sc3, sh3, out);
  } else {
    k_stage<1,0,false><<<NBLK, 64, 0, stream>>>(xyz, featT, nxyz, ball, nullptr, nullptr,
                                                W1T, W2T, W3T, sc1, sh1, sc2, sh2, sums1);
    k_fin<64><<<1, 64, 0, stream>>>(sums1, g1, b1, sc1, sh1);
    k_stage<2,0,false><<<NBLK, 64, 0, stream>>>(xyz, featT, nxyz, ball, nullptr, nullptr,
                                                W1T, W2T, W3T, sc1, sh1, sc2, sh2, sums2);
    k_fin<64><<<1, 64, 0, stream>>>(sums2, g2, b2, sc2, sh2);
    k_stage<3,0,false><<<NBLK, 64, 0, stream>>>(xyz, featT, nxyz, ball, nullptr, nullptr,
                                                W1T, W2T, W3T, sc1, sh1, sc2, sh2, sums3);
    k_fin<128><<<1, 128, 0, stream>>>(sums3, g3, b3, sc3, sh3);
    k_pass2<false><<<8192, 64, 0, stream>>>(xyz, featT, nxyz, ball, nullptr, W1T, W2T, W3,
                                            sc1, sh1, sc2, sh2, sc3, sh3, out);
  }
}